// Round 13
// baseline (585.644 us; speedup 1.0000x reference)
//
#include <hip/hip_runtime.h>
#include <stdint.h>
#include <math.h>

typedef unsigned short u16;
typedef __bf16 bf16x8 __attribute__((ext_vector_type(8)));
typedef float f32x4 __attribute__((ext_vector_type(4)));
typedef short s16x8 __attribute__((ext_vector_type(8)));
union B8 { s16x8 s; bf16x8 b; };

// ---------- helpers ----------
__device__ __forceinline__ u16 f2bf(float f) {
    union { __bf16 h; u16 u; } r;
    r.h = (__bf16)f;
    return r.u;
}
__device__ __forceinline__ uint32_t pk2bf(float a, float b) {
    union { __bf16 h[2]; uint32_t u; } r;
    r.h[0] = (__bf16)a; r.h[1] = (__bf16)b;
    return r.u;
}
__device__ __forceinline__ float bf2f(u16 u) {
    return __uint_as_float(((uint32_t)u) << 16);
}
__device__ __forceinline__ float fexp2(float x) {
    return __builtin_amdgcn_exp2f(x);
}

typedef const __attribute__((address_space(1))) uint32_t* gas_t;
typedef __attribute__((address_space(3))) uint32_t* las_t;
__device__ __forceinline__ void gld16(const void* g, void* l) {
    __builtin_amdgcn_global_load_lds((gas_t)g, (las_t)l, 16, 0, 0);
}

__host__ __forceinline__ uint32_t rotl32(uint32_t x, int d) {
    return (x << d) | (x >> (32 - d));
}
__device__ __forceinline__ uint32_t rotl_d(uint32_t x, int d) {
    return __builtin_amdgcn_alignbit(x, x, (uint32_t)(32 - d));
}

// JAX threefry2x32 (20 rounds) — host version (key folding)
__host__ inline void tf2x32_h(uint32_t k0, uint32_t k1, uint32_t& x0, uint32_t& x1) {
    uint32_t k2 = k0 ^ k1 ^ 0x1BD11BDAu;
    x0 += k0; x1 += k1;
    x0 += x1; x1 = rotl32(x1, 13); x1 ^= x0;
    x0 += x1; x1 = rotl32(x1, 15); x1 ^= x0;
    x0 += x1; x1 = rotl32(x1, 26); x1 ^= x0;
    x0 += x1; x1 = rotl32(x1,  6); x1 ^= x0;
    x0 += k1; x1 += k2 + 1u;
    x0 += x1; x1 = rotl32(x1, 17); x1 ^= x0;
    x0 += x1; x1 = rotl32(x1, 29); x1 ^= x0;
    x0 += x1; x1 = rotl32(x1, 16); x1 ^= x0;
    x0 += x1; x1 = rotl32(x1, 24); x1 ^= x0;
    x0 += k2; x1 += k0 + 2u;
    x0 += x1; x1 = rotl32(x1, 13); x1 ^= x0;
    x0 += x1; x1 = rotl32(x1, 15); x1 ^= x0;
    x0 += x1; x1 = rotl32(x1, 26); x1 ^= x0;
    x0 += x1; x1 = rotl32(x1,  6); x1 ^= x0;
    x0 += k0; x1 += k1 + 3u;
    x0 += x1; x1 = rotl32(x1, 17); x1 ^= x0;
    x0 += x1; x1 = rotl32(x1, 29); x1 ^= x0;
    x0 += x1; x1 = rotl32(x1, 16); x1 ^= x0;
    x0 += x1; x1 = rotl32(x1, 24); x1 ^= x0;
    x0 += k1; x1 += k2 + 4u;
    x0 += x1; x1 = rotl32(x1, 13); x1 ^= x0;
    x0 += x1; x1 = rotl32(x1, 15); x1 ^= x0;
    x0 += x1; x1 = rotl32(x1, 26); x1 ^= x0;
    x0 += x1; x1 = rotl32(x1,  6); x1 ^= x0;
    x0 += k2; x1 += k0 + 5u;
}

__device__ __forceinline__ void tf2x32_d(uint32_t k0, uint32_t k1,
                                         uint32_t& x0, uint32_t& x1) {
    uint32_t k2 = k0 ^ k1 ^ 0x1BD11BDAu;
    x0 += k0; x1 += k1;
    x0 += x1; x1 = rotl_d(x1, 13); x1 ^= x0;
    x0 += x1; x1 = rotl_d(x1, 15); x1 ^= x0;
    x0 += x1; x1 = rotl_d(x1, 26); x1 ^= x0;
    x0 += x1; x1 = rotl_d(x1,  6); x1 ^= x0;
    x0 += k1; x1 += k2 + 1u;
    x0 += x1; x1 = rotl_d(x1, 17); x1 ^= x0;
    x0 += x1; x1 = rotl_d(x1, 29); x1 ^= x0;
    x0 += x1; x1 = rotl_d(x1, 16); x1 ^= x0;
    x0 += x1; x1 = rotl_d(x1, 24); x1 ^= x0;
    x0 += k2; x1 += k0 + 2u;
    x0 += x1; x1 = rotl_d(x1, 13); x1 ^= x0;
    x0 += x1; x1 = rotl_d(x1, 15); x1 ^= x0;
    x0 += x1; x1 = rotl_d(x1, 26); x1 ^= x0;
    x0 += x1; x1 = rotl_d(x1,  6); x1 ^= x0;
    x0 += k0; x1 += k1 + 3u;
    x0 += x1; x1 = rotl_d(x1, 17); x1 ^= x0;
    x0 += x1; x1 = rotl_d(x1, 29); x1 ^= x0;
    x0 += x1; x1 = rotl_d(x1, 16); x1 ^= x0;
    x0 += x1; x1 = rotl_d(x1, 24); x1 ^= x0;
    x0 += k1; x1 += k2 + 4u;
    x0 += x1; x1 = rotl_d(x1, 13); x1 ^= x0;
    x0 += x1; x1 = rotl_d(x1, 15); x1 ^= x0;
    x0 += x1; x1 = rotl_d(x1, 26); x1 ^= x0;
    x0 += x1; x1 = rotl_d(x1,  6); x1 ^= x0;
    x0 += k2; x1 += k0 + 5u;
}

// XLA ErfInv f32 (Giles polynomial); log1p(-x^2) -> fast v_log_f32 path
__device__ __forceinline__ float erfinv_f(float x) {
    float w = -__logf(fmaf(x, -x, 1.0f));
    float p;
    if (w < 5.0f) {
        w = w - 2.5f;
        p = 2.81022636e-08f;
        p = p * w + 3.43273939e-07f;
        p = p * w + -3.5233877e-06f;
        p = p * w + -4.39150654e-06f;
        p = p * w + 0.00021858087f;
        p = p * w + -0.00125372503f;
        p = p * w + -0.00417768164f;
        p = p * w + 0.246640727f;
        p = p * w + 1.50140941f;
    } else {
        w = sqrtf(w) - 3.0f;
        p = -0.000200214257f;
        p = p * w + 0.000100950558f;
        p = p * w + 0.00134934322f;
        p = p * w + -0.00367342844f;
        p = p * w + 0.00573950773f;
        p = p * w + -0.0076224613f;
        p = p * w + 0.00943887047f;
        p = p * w + 1.00167406f;
        p = p * w + 2.83297682f;
    }
    return p * x;
}

__device__ __forceinline__ float tf_normal(uint32_t k0, uint32_t k1, uint32_t idx) {
    uint32_t x0 = 0u, x1 = idx;
    tf2x32_d(k0, k1, x0, x1);
    uint32_t bits = x0 ^ x1;
    float f = __uint_as_float((bits >> 9) | 0x3f800000u) - 1.0f;
    float u = f * 2.0f - 0.99999994f;
    u = fmaxf(-0.99999994f, u);
    return 1.41421354f * erfinv_f(u);
}

// ---------- noise init ----------
__global__ __launch_bounds__(256) void noise_kernel(
    u16* __restrict__ xb,
    uint32_t ka0, uint32_t ka1, float ca,
    uint32_t kb0, uint32_t kb1, float cb, int n4)
{
    int i = blockIdx.x * 256 + threadIdx.x;
    if (i >= n4) return;
    ushort4 vb;
    #pragma unroll
    for (int e = 0; e < 4; ++e) {
        uint32_t idx = (uint32_t)(i * 4 + e);
        float a = ca * tf_normal(ka0, ka1, idx)
                + cb * tf_normal(kb0, kb1, idx);
        (&vb.x)[e] = f2bf(a);
    }
    ((ushort4*)xb)[i] = vb;
}

// ---------- merged weight convert ----------
__global__ __launch_bounds__(256) void cvt_all_kernel(
    const float* __restrict__ Wq, const float* __restrict__ Wk,
    const float* __restrict__ Wv, const float* __restrict__ Wo,
    const float* __restrict__ W1, const float* __restrict__ W2,
    const float* __restrict__ Wout, u16* __restrict__ dst, int n4)
{
    int i = blockIdx.x * 256 + threadIdx.x;
    if (i >= n4) return;
    int e = i * 4;
    const float* src;
    if (e < 3145728) {
        int l = e / 786432;
        int rem = e - l * 786432;
        int sel = rem >> 18;
        int off = rem & 262143;
        src = (sel == 0 ? Wq : sel == 1 ? Wk : Wv) + l * 262144 + off;
    } else if (e < 4194304) src = Wo + (e - 3145728);
    else if (e < 8388608)  src = W1 + (e - 4194304);
    else if (e < 12582912) src = W2 + (e - 8388608);
    else                   src = Wout + (e - 12582912);
    float4 v = *(const float4*)src;
    uint2 o;
    o.x = pk2bf(v.x, v.y);
    o.y = pk2bf(v.z, v.w);
    *(uint2*)(dst + e) = o;
}

// ---------- GEMM 128x64: 8 waves, dbuf, XCD swizzle ----------
// EPI: 0 = f32 out; 1 = bf16 out + bf16 resid
template<int EPI>
__global__ __launch_bounds__(512) void gemm64u(
    const u16* __restrict__ A, const u16* __restrict__ Bw,
    const float* __restrict__ bias0, const u16* __restrict__ resid,
    void* __restrict__ out0, int N, int K)
{
    constexpr int ACH = 16;
    constexpr int ASZ = 128 * 64, BSZ = 64 * 64;
    __shared__ __align__(16) u16 At[2 * ASZ];
    __shared__ __align__(16) u16 Bt[2 * BSZ];
    const int tid = threadIdx.x;
    const int l = tid & 63;
    const int w = tid >> 6;
    const int wr = w >> 1, wc = w & 1;

    int lid = blockIdx.y * gridDim.x + blockIdx.x;
    int nwg = gridDim.x * gridDim.y;
    int nlid = (lid & 7) * (nwg >> 3) + (lid >> 3);
    int mb = nlid / gridDim.x;
    int nb = nlid - mb * gridDim.x;

    const int lrow = l >> 3;
    const int lch  = (l & 7) ^ lrow;

    const u16* aTile = A  + (size_t)(mb * 128) * K + (size_t)lrow * K + lch * 8;
    const u16* bTile = Bw + (size_t)(nb * 64) * K + (size_t)lrow * K + lch * 8;

    f32x4 acc[2][2] = {};

    auto stage = [&](int buf, int k0) {
        #pragma unroll
        for (int i = 0; i < 3; ++i) {
            int c = w * 3 + i;
            if (c < ACH) gld16(aTile + (size_t)(c * 8) * K + k0, &At[buf * ASZ + c * 512]);
            else gld16(bTile + (size_t)((c - ACH) * 8) * K + k0, &Bt[buf * BSZ + (c - ACH) * 512]);
        }
    };
    auto compute = [&](int buf) {
        const u16* Ac = &At[buf * ASZ];
        const u16* Bc = &Bt[buf * BSZ];
        #pragma unroll
        for (int kc = 0; kc < 2; ++kc) {
            B8 af[2], bfr[2];
            #pragma unroll
            for (int m = 0; m < 2; ++m) {
                int r = wr * 32 + m * 16 + (l & 15);
                int ch = kc * 4 + (l >> 4);
                af[m].s = *(const s16x8*)&Ac[r * 64 + ((ch ^ (r & 7)) * 8)];
            }
            #pragma unroll
            for (int n = 0; n < 2; ++n) {
                int r = wc * 32 + n * 16 + (l & 15);
                int ch = kc * 4 + (l >> 4);
                bfr[n].s = *(const s16x8*)&Bc[r * 64 + ((ch ^ (r & 7)) * 8)];
            }
            #pragma unroll
            for (int m = 0; m < 2; ++m)
                #pragma unroll
                for (int n = 0; n < 2; ++n)
                    acc[m][n] = __builtin_amdgcn_mfma_f32_16x16x32_bf16(
                        af[m].b, bfr[n].b, acc[m][n], 0, 0, 0);
        }
    };

    stage(0, 0);
    __syncthreads();
    int cur = 0;
    for (int k0 = 0; k0 < K; k0 += 64) {
        if (k0 + 64 < K) stage(cur ^ 1, k0 + 64);
        compute(cur);
        __syncthreads();
        cur ^= 1;
    }

    float bcol[2];
    #pragma unroll
    for (int n = 0; n < 2; ++n)
        bcol[n] = bias0[nb * 64 + wc * 32 + n * 16 + (l & 15)];

    #pragma unroll
    for (int m = 0; m < 2; ++m) {
        #pragma unroll
        for (int j = 0; j < 4; ++j) {
            int row = mb * 128 + wr * 32 + m * 16 + (l >> 4) * 4 + j;
            #pragma unroll
            for (int n = 0; n < 2; ++n) {
                int col = nb * 64 + wc * 32 + n * 16 + (l & 15);
                float v = acc[m][n][j] + bcol[n];
                if constexpr (EPI == 1) {
                    v += bf2f(resid[(size_t)row * N + col]);
                    ((u16*)out0)[(size_t)row * N + col] = f2bf(v);
                } else {
                    ((float*)out0)[(size_t)row * N + col] = v;
                }
            }
        }
    }
}

// ---------- GEMM 128x128: 8 waves (4x2, 32x64 each), dbuf, XCD swizzle -------
// EPI: 2 = bf16 out + relu (W1); 3 = QKV split
template<int EPI>
__global__ __launch_bounds__(512) void gemm128(
    const u16* __restrict__ A, const u16* __restrict__ Bw,
    const float* __restrict__ bias0, const float* __restrict__ bias1,
    const float* __restrict__ bias2,
    void* __restrict__ out0, void* __restrict__ out1, void* __restrict__ out2,
    int N, int K)
{
    constexpr int ACH = 16;
    constexpr int ASZ = 128 * 64, BSZ = 128 * 64;
    __shared__ __align__(16) u16 At[2 * ASZ];
    __shared__ __align__(16) u16 Bt[2 * BSZ];
    const int tid = threadIdx.x;
    const int l = tid & 63;
    const int w = tid >> 6;             // 0..7
    const int wr = w >> 1;              // 0..3 (32-row group)
    const int wc = w & 1;               // 0..1 (64-col group)

    int lid = blockIdx.y * gridDim.x + blockIdx.x;
    int nwg = gridDim.x * gridDim.y;
    int nlid = (lid & 7) * (nwg >> 3) + (lid >> 3);
    int mb = nlid / gridDim.x;
    int nb = nlid - mb * gridDim.x;

    const int lrow = l >> 3;
    const int lch  = (l & 7) ^ lrow;

    const u16* aTile = A  + (size_t)(mb * 128) * K + (size_t)lrow * K + lch * 8;
    const u16* bTile = Bw + (size_t)(nb * 128) * K + (size_t)lrow * K + lch * 8;

    f32x4 acc[2][4] = {};

    auto stage = [&](int buf, int k0) {
        #pragma unroll
        for (int i = 0; i < 4; ++i) {
            int c = w * 4 + i;                 // 0..31
            if (c < ACH) gld16(aTile + (size_t)(c * 8) * K + k0, &At[buf * ASZ + c * 512]);
            else gld16(bTile + (size_t)((c - ACH) * 8) * K + k0, &Bt[buf * BSZ + (c - ACH) * 512]);
        }
    };
    auto compute = [&](int buf) {
        const u16* Ac = &At[buf * ASZ];
        const u16* Bc = &Bt[buf * BSZ];
        #pragma unroll
        for (int kc = 0; kc < 2; ++kc) {
            B8 af[2], bfr[4];
            #pragma unroll
            for (int m = 0; m < 2; ++m) {
                int r = wr * 32 + m * 16 + (l & 15);
                int ch = kc * 4 + (l >> 4);
                af[m].s = *(const s16x8*)&Ac[r * 64 + ((ch ^ (r & 7)) * 8)];
            }
            #pragma unroll
            for (int n = 0; n < 4; ++n) {
                int r = wc * 64 + n * 16 + (l & 15);
                int ch = kc * 4 + (l >> 4);
                bfr[n].s = *(const s16x8*)&Bc[r * 64 + ((ch ^ (r & 7)) * 8)];
            }
            #pragma unroll
            for (int m = 0; m < 2; ++m)
                #pragma unroll
                for (int n = 0; n < 4; ++n)
                    acc[m][n] = __builtin_amdgcn_mfma_f32_16x16x32_bf16(
                        af[m].b, bfr[n].b, acc[m][n], 0, 0, 0);
        }
    };

    stage(0, 0);
    __syncthreads();
    int cur = 0;
    for (int k0 = 0; k0 < K; k0 += 64) {
        if (k0 + 64 < K) stage(cur ^ 1, k0 + 64);
        compute(cur);
        __syncthreads();
        cur ^= 1;
    }

    if constexpr (EPI == 3) {
        int which = nb >> 2;                       // 0=Q 1=K 2=V
        int colseg = (nb & 3) * 128 + wc * 64;     // within 512
        const float* biasp = which == 0 ? bias0 : which == 1 ? bias1 : bias2;
        float bcol[4];
        #pragma unroll
        for (int n = 0; n < 4; ++n)
            bcol[n] = biasp[colseg + n * 16 + (l & 15)];
        if (which == 2) {
            u16* vT = (u16*)out2;
            #pragma unroll
            for (int m = 0; m < 2; ++m) {
                int row0 = mb * 128 + wr * 32 + m * 16 + (l >> 4) * 4;
                int bb = row0 >> 10, s0 = row0 & 1023;
                #pragma unroll
                for (int n = 0; n < 4; ++n) {
                    int col = colseg + n * 16 + (l & 15);
                    int hh = col >> 6, dd = col & 63;
                    uint2 o;
                    o.x = pk2bf(acc[m][n][0] + bcol[n], acc[m][n][1] + bcol[n]);
                    o.y = pk2bf(acc[m][n][2] + bcol[n], acc[m][n][3] + bcol[n]);
                    *(uint2*)&vT[((size_t)((bb * 8 + hh) * 64 + dd)) * 1024 + s0] = o;
                }
            }
            return;
        }
        float oscale = (which == 0) ? 0.18033688f : 1.0f;  // 0.125*log2(e)
        u16* outp = (u16*)(which == 0 ? out0 : out1);
        #pragma unroll
        for (int m = 0; m < 2; ++m) {
            #pragma unroll
            for (int j = 0; j < 4; ++j) {
                int row = mb * 128 + wr * 32 + m * 16 + (l >> 4) * 4 + j;
                #pragma unroll
                for (int n = 0; n < 4; ++n) {
                    int col = colseg + n * 16 + (l & 15);
                    outp[(size_t)row * 512 + col] = f2bf((acc[m][n][j] + bcol[n]) * oscale);
                }
            }
        }
        return;
    }

    // EPI == 2: bf16 out + relu
    float bcol[4];
    #pragma unroll
    for (int n = 0; n < 4; ++n)
        bcol[n] = bias0[nb * 128 + wc * 64 + n * 16 + (l & 15)];
    #pragma unroll
    for (int m = 0; m < 2; ++m) {
        #pragma unroll
        for (int j = 0; j < 4; ++j) {
            int row = mb * 128 + wr * 32 + m * 16 + (l >> 4) * 4 + j;
            #pragma unroll
            for (int n = 0; n < 4; ++n) {
                int col = nb * 128 + wc * 64 + n * 16 + (l & 15);
                float v = fmaxf(acc[m][n][j] + bcol[n], 0.0f);
                ((u16*)out0)[(size_t)row * N + col] = f2bf(v);
            }
        }
    }
}

// ---------- LayerNorm: bf16 in -> bf16 out ----------
__global__ __launch_bounds__(256) void ln_kernel(
    const u16* __restrict__ y, const float* __restrict__ g,
    const float* __restrict__ b, u16* __restrict__ xb)
{
    int row = blockIdx.x * 4 + (threadIdx.x >> 6);
    int l = threadIdx.x & 63;
    uint4 vv = ((const uint4*)(y + (size_t)row * 512))[l];
    uint32_t wsr[4] = {vv.x, vv.y, vv.z, vv.w};
    float xv[8];
    #pragma unroll
    for (int k = 0; k < 4; ++k) {
        xv[2 * k]     = __uint_as_float(wsr[k] << 16);
        xv[2 * k + 1] = __uint_as_float(wsr[k] & 0xFFFF0000u);
    }
    float s = 0.0f, q = 0.0f;
    #pragma unroll
    for (int k = 0; k < 8; ++k) { s += xv[k]; q += xv[k] * xv[k]; }
    #pragma unroll
    for (int m = 1; m < 64; m <<= 1) {
        s += __shfl_xor(s, m, 64);
        q += __shfl_xor(q, m, 64);
    }
    float mean = s * (1.0f / 512.0f);
    float var  = q * (1.0f / 512.0f) - mean * mean;
    float rstd = rsqrtf(var + 1e-5f);
    const float4* gv = (const float4*)g;
    const float4* bv = (const float4*)b;
    float4 g0 = gv[2 * l], g1 = gv[2 * l + 1];
    float4 b0 = bv[2 * l], b1 = bv[2 * l + 1];
    float ov[8];
    ov[0] = (xv[0] - mean) * rstd * g0.x + b0.x;
    ov[1] = (xv[1] - mean) * rstd * g0.y + b0.y;
    ov[2] = (xv[2] - mean) * rstd * g0.z + b0.z;
    ov[3] = (xv[3] - mean) * rstd * g0.w + b0.w;
    ov[4] = (xv[4] - mean) * rstd * g1.x + b1.x;
    ov[5] = (xv[5] - mean) * rstd * g1.y + b1.y;
    ov[6] = (xv[6] - mean) * rstd * g1.z + b1.z;
    ov[7] = (xv[7] - mean) * rstd * g1.w + b1.w;
    uint4 o;
    o.x = pk2bf(ov[0], ov[1]);
    o.y = pk2bf(ov[2], ov[3]);
    o.z = pk2bf(ov[4], ov[5]);
    o.w = pk2bf(ov[6], ov[7]);
    ((uint4*)(xb + (size_t)row * 512))[l] = o;
}

// ---------- fused attention v7 ----------
__global__ __launch_bounds__(512) void attn_kernel(
    const u16* __restrict__ Q, const u16* __restrict__ Km,
    const u16* __restrict__ vT, u16* __restrict__ O)
{
    __shared__ __align__(16) u16 Kt[2][64 * 64];
    __shared__ __align__(16) u16 Vt[2][64 * 64];
    __shared__ __align__(16) char Pl[8][2048];
    const int tid = threadIdx.x;
    const int l = tid & 63;
    const int w = tid >> 6;
    const int g = l >> 4;
    const int q15 = l & 15;
    const int bh = blockIdx.x;
    const int qb = blockIdx.y;
    const int b = bh >> 3, h = bh & 7;
    const int rowQ0 = b * 1024 + qb * 128 + w * 16;
    const int colh = h * 64;
    char* pl = &Pl[w][0];
    const int rbase = q15 * 128;
    const int sw = (q15 & 7) << 4;

    const int srow = l >> 3;
    const u16* Kbase = Km + (size_t)(b * 1024) * 512 + colh;
    const u16* Vbase = vT + (size_t)bh * 64 * 1024;

    B8 qf[2];
    #pragma unroll
    for (int kc = 0; kc < 2; ++kc)
        qf[kc].s = *(const s16x8*)&Q[(size_t)(rowQ0 + q15) * 512
                                     + colh + kc * 32 + g * 8];

    f32x4 oacc[4] = {};
    float lrun = 0.0f;

    auto stage = [&](int buf, int kt) {
        int r = w * 8 + srow;
        int cc = (l & 7) ^ (r & 7);
        gld16(Kbase + (size_t)(kt * 64 + r) * 512 + cc * 8, &Kt[buf][w * 512]);
        gld16(Vbase + (size_t)r * 1024 + kt * 64 + cc * 8, &Vt[buf][w * 512]);
    };

    stage(0, 0);
    __syncthreads();
    int cur = 0;

    for (int kt = 0; kt < 16; ++kt) {
        if (kt < 15) stage(cur ^ 1, kt + 1);
        const u16* KtL = &Kt[cur][0];
        const u16* VtL = &Vt[cur][0];

        f32x4 st[4];
        __builtin_amdgcn_s_setprio(1);
        #pragma unroll
        for (int mt = 0; mt < 4; ++mt) {
            int r = mt * 16 + q15;
            B8 kf0, kf1;
            kf0.s = *(const s16x8*)&KtL[r * 64 + ((g ^ (r & 7)) * 8)];
            kf1.s = *(const s16x8*)&KtL[r * 64 + (((4 + g) ^ (r & 7)) * 8)];
            f32x4 t = {0.f, 0.f, 0.f, 0.f};
            t = __builtin_amdgcn_mfma_f32_16x16x32_bf16(kf0.b, qf[0].b, t, 0, 0, 0);
            t = __builtin_amdgcn_mfma_f32_16x16x32_bf16(kf1.b, qf[1].b, t, 0, 0, 0);
            st[mt] = t;
        }
        __builtin_amdgcn_s_setprio(0);

        float rs = 0.0f;
        #pragma unroll
        for (int mt = 0; mt < 4; ++mt) {
            float e0 = fexp2(st[mt][0]);
            float e1 = fexp2(st[mt][1]);
            float e2 = fexp2(st[mt][2]);
            float e3 = fexp2(st[mt][3]);
            rs += (e0 + e1) + (e2 + e3);
            uint2 pk;
            pk.x = pk2bf(e0, e1);
            pk.y = pk2bf(e2, e3);
            *(uint2*)(pl + rbase + ((mt * 32 + g * 8) ^ sw)) = pk;
        }
        rs += __shfl_xor(rs, 16, 64);
        rs += __shfl_xor(rs, 32, 64);
        lrun += rs;

        B8 pf0, pf1;
        pf0.s = *(const s16x8*)(pl + rbase + ((g * 16) ^ sw));
        pf1.s = *(const s16x8*)(pl + rbase + (((4 + g) * 16) ^ sw));

        __builtin_amdgcn_s_setprio(1);
        #pragma unroll
        for (int dt = 0; dt < 4; ++dt) {
            int r = dt * 16 + q15;
            B8 vf0, vf1;
            vf0.s = *(const s16x8*)&VtL[r * 64 + ((g ^ (r & 7)) * 8)];
            vf1.s = *(const s16x8*)&VtL[r * 64 + (((4 + g) ^ (r & 7)) * 8)];
            oacc[dt] = __builtin_amdgcn_mfma_f32_16x16x32_bf16(
                vf0.b, pf0.b, oacc[dt], 0, 0, 0);
            oacc[dt] = __builtin_amdgcn_mfma_f32_16x16x32_bf16(
                vf1.b, pf1.b, oacc[dt], 0, 0, 0);
        }
        __builtin_amdgcn_s_setprio(0);
        __syncthreads();
        cur ^= 1;
    }

    float inv = 1.0f / lrun;
    int row = rowQ0 + q15;
    #pragma unroll
    for (int dt = 0; dt < 4; ++dt) {
        uint2 o;
        o.x = pk2bf(oacc[dt][0] * inv, oacc[dt][1] * inv);
        o.y = pk2bf(oacc[dt][2] * inv, oacc[dt][3] * inv);
        *(uint2*)&O[(size_t)row * 512 + colh + dt * 16 + g * 4] = o;
    }
}

// ---------- launcher ----------
extern "C" void kernel_launch(void* const* d_in, const int* in_sizes, int n_in,
                              void* d_out, int out_size, void* d_ws, size_t ws_size,
                              hipStream_t stream)
{
    const int D = 512, F = 2048, Lc = 4;
    const int Mrows = 8 * 1024;

    const float* Wq   = (const float*)d_in[1];
    const float* Wk   = (const float*)d_in[2];
    const float* Wv   = (const float*)d_in[3];
    const float* bq   = (const float*)d_in[4];
    const float* bk   = (const float*)d_in[5];
    const float* bv   = (const float*)d_in[6];
    const float* Wo   = (const float*)d_in[7];
    const float* bo   = (const float*)d_in[8];
    const float* ln1g = (const float*)d_in[9];
    const float* ln1b = (const float*)d_in[10];
    const float* ln2g = (const float*)d_in[11];
    const float* ln2b = (const float*)d_in[12];
    const float* W1   = (const float*)d_in[13];
    const float* b1   = (const float*)d_in[14];
    const float* W2   = (const float*)d_in[15];
    const float* b2   = (const float*)d_in[16];
    const float* Wout = (const float*)d_in[17];
    const float* bout = (const float*)d_in[18];

    char* p = (char*)d_ws;
    auto alloc = [&](size_t bytes) {
        char* r = p;
        p += (bytes + 255) & ~(size_t)255;
        return r;
    };
    u16* xb = (u16*)alloc((size_t)Mrows * D * 2);
    u16* y  = (u16*)alloc((size_t)Mrows * D * 2);
    char* pool = alloc((size_t)Mrows * F * 2);
    u16* qb_ = (u16*)pool;
    u16* kb_ = (u16*)(pool + (size_t)Mrows * D * 2);
    u16* vT  = (u16*)(pool + (size_t)Mrows * D * 2 * 2);
    u16* ao  = (u16*)(pool + (size_t)Mrows * D * 2 * 3);
    u16* ff1 = (u16*)pool;
    u16* wAll  = (u16*)alloc((size_t)12845056 * 2);
    u16* wqkvB = wAll;
    u16* woB   = wAll + 3145728;
    u16* w1B   = wAll + 4194304;
    u16* w2B   = wAll + 8388608;
    u16* woutB = wAll + 12582912;

    {
        int n4 = 12845056 / 4;
        cvt_all_kernel<<<(n4 + 255) / 256, 256, 0, stream>>>(
            Wq, Wk, Wv, Wo, W1, W2, Wout, wAll, n4);
    }

    // DDIM noise coefficients
    float ac[1000];
    {
        float start = 1e-4f, stop = 0.02f;
        float delta = (stop - start) / 999.0f;
        float prod = 1.0f;
        for (int i = 0; i < 1000; ++i) {
            float beta = start + (float)i * delta;
            prod *= (1.0f - beta);
            ac[i] = prod;
        }
    }
    int ts[2] = {999, 998};
    double cs[2];
    double tail = 1.0;
    for (int idx = 0; idx < 2; ++idx) {
        int t = ts[idx];
        cs[idx] = sqrt(1.0 - (double)ac[t]) * tail;
        tail *= sqrt((double)ac[t]);
    }
    uint32_t kk[2][2];
    for (int idx = 0; idx < 2; ++idx) {
        uint32_t x0 = 0u, x1 = (uint32_t)ts[idx];
        tf2x32_h(0u, 42u, x0, x1);
        kk[idx][0] = x0; kk[idx][1] = x1;
    }
    int n4tot = Mrows * D / 4;
    noise_kernel<<<(n4tot + 255) / 256, 256, 0, stream>>>(
        xb,
        kk[0][0], kk[0][1], (float)cs[0],
        kk[1][0], kk[1][1], (float)cs[1], n4tot);

    dim3 gqkv(3 * D / 128, Mrows / 128);   // (12, 64) = 768
    dim3 g64(D / 64, Mrows / 128);         // (8, 64) = 512
    dim3 gff1(F / 128, Mrows / 128);       // (16, 64) = 1024

    for (int l = 0; l < Lc; ++l) {
        const u16* wqkv_l = wqkvB + (size_t)l * 3 * D * D;
        const u16* wo_l = woB + (size_t)l * D * D;
        const u16* w1_l = w1B + (size_t)l * F * D;
        const u16* w2_l = w2B + (size_t)l * D * F;

        gemm128<3><<<gqkv, 512, 0, stream>>>(
            xb, wqkv_l, bq + l * D, bk + l * D, bv + l * D,
            qb_, kb_, vT, 3 * D, D);
        attn_kernel<<<dim3(64, 8), 512, 0, stream>>>(qb_, kb_, vT, ao);
        gemm64u<1><<<g64, 512, 0, stream>>>(
            ao, wo_l, bo + l * D, xb, y, D, D);
        ln_kernel<<<Mrows / 4, 256, 0, stream>>>(y, ln1g + l * D, ln1b + l * D, xb);
        gemm128<2><<<gff1, 512, 0, stream>>>(
            xb, w1_l, b1 + l * F, nullptr, nullptr,
            ff1, nullptr, nullptr, F, D);
        gemm64u<1><<<g64, 512, 0, stream>>>(
            ff1, w2_l, b2 + l * D, xb, y, D, F);
        ln_kernel<<<Mrows / 4, 256, 0, stream>>>(y, ln2g + l * D, ln2b + l * D, xb);
    }
    gemm64u<0><<<g64, 512, 0, stream>>>(
        xb, woutB, bout, nullptr, (float*)d_out, D, D);
}

// Round 14
// 578.323 us; speedup vs baseline: 1.0127x; 1.0127x over previous
//
#include <hip/hip_runtime.h>
#include <stdint.h>
#include <math.h>

typedef unsigned short u16;
typedef __bf16 bf16x8 __attribute__((ext_vector_type(8)));
typedef float f32x4 __attribute__((ext_vector_type(4)));
typedef short s16x8 __attribute__((ext_vector_type(8)));
union B8 { s16x8 s; bf16x8 b; };

// ---------- helpers ----------
__device__ __forceinline__ u16 f2bf(float f) {
    union { __bf16 h; u16 u; } r;
    r.h = (__bf16)f;
    return r.u;
}
__device__ __forceinline__ uint32_t pk2bf(float a, float b) {
    union { __bf16 h[2]; uint32_t u; } r;
    r.h[0] = (__bf16)a; r.h[1] = (__bf16)b;
    return r.u;
}
__device__ __forceinline__ float bf2f(u16 u) {
    return __uint_as_float(((uint32_t)u) << 16);
}
__device__ __forceinline__ float fexp2(float x) {
    return __builtin_amdgcn_exp2f(x);   // raw v_exp_f32
}

typedef const __attribute__((address_space(1))) uint32_t* gas_t;
typedef __attribute__((address_space(3))) uint32_t* las_t;
__device__ __forceinline__ void gld16(const void* g, void* l) {
    __builtin_amdgcn_global_load_lds((gas_t)g, (las_t)l, 16, 0, 0);
}

__host__ __forceinline__ uint32_t rotl32(uint32_t x, int d) {
    return (x << d) | (x >> (32 - d));
}
__device__ __forceinline__ uint32_t rotl_d(uint32_t x, int d) {
    return __builtin_amdgcn_alignbit(x, x, (uint32_t)(32 - d));
}

// JAX threefry2x32 (20 rounds) — host version (key folding)
__host__ inline void tf2x32_h(uint32_t k0, uint32_t k1, uint32_t& x0, uint32_t& x1) {
    uint32_t k2 = k0 ^ k1 ^ 0x1BD11BDAu;
    x0 += k0; x1 += k1;
    x0 += x1; x1 = rotl32(x1, 13); x1 ^= x0;
    x0 += x1; x1 = rotl32(x1, 15); x1 ^= x0;
    x0 += x1; x1 = rotl32(x1, 26); x1 ^= x0;
    x0 += x1; x1 = rotl32(x1,  6); x1 ^= x0;
    x0 += k1; x1 += k2 + 1u;
    x0 += x1; x1 = rotl32(x1, 17); x1 ^= x0;
    x0 += x1; x1 = rotl32(x1, 29); x1 ^= x0;
    x0 += x1; x1 = rotl32(x1, 16); x1 ^= x0;
    x0 += x1; x1 = rotl32(x1, 24); x1 ^= x0;
    x0 += k2; x1 += k0 + 2u;
    x0 += x1; x1 = rotl32(x1, 13); x1 ^= x0;
    x0 += x1; x1 = rotl32(x1, 15); x1 ^= x0;
    x0 += x1; x1 = rotl32(x1, 26); x1 ^= x0;
    x0 += x1; x1 = rotl32(x1,  6); x1 ^= x0;
    x0 += k0; x1 += k1 + 3u;
    x0 += x1; x1 = rotl32(x1, 17); x1 ^= x0;
    x0 += x1; x1 = rotl32(x1, 29); x1 ^= x0;
    x0 += x1; x1 = rotl32(x1, 16); x1 ^= x0;
    x0 += x1; x1 = rotl32(x1, 24); x1 ^= x0;
    x0 += k1; x1 += k2 + 4u;
    x0 += x1; x1 = rotl32(x1, 13); x1 ^= x0;
    x0 += x1; x1 = rotl32(x1, 15); x1 ^= x0;
    x0 += x1; x1 = rotl32(x1, 26); x1 ^= x0;
    x0 += x1; x1 = rotl32(x1,  6); x1 ^= x0;
    x0 += k2; x1 += k0 + 5u;
}

__device__ __forceinline__ void tf2x32_d(uint32_t k0, uint32_t k1,
                                         uint32_t& x0, uint32_t& x1) {
    uint32_t k2 = k0 ^ k1 ^ 0x1BD11BDAu;
    x0 += k0; x1 += k1;
    x0 += x1; x1 = rotl_d(x1, 13); x1 ^= x0;
    x0 += x1; x1 = rotl_d(x1, 15); x1 ^= x0;
    x0 += x1; x1 = rotl_d(x1, 26); x1 ^= x0;
    x0 += x1; x1 = rotl_d(x1,  6); x1 ^= x0;
    x0 += k1; x1 += k2 + 1u;
    x0 += x1; x1 = rotl_d(x1, 17); x1 ^= x0;
    x0 += x1; x1 = rotl_d(x1, 29); x1 ^= x0;
    x0 += x1; x1 = rotl_d(x1, 16); x1 ^= x0;
    x0 += x1; x1 = rotl_d(x1, 24); x1 ^= x0;
    x0 += k2; x1 += k0 + 2u;
    x0 += x1; x1 = rotl_d(x1, 13); x1 ^= x0;
    x0 += x1; x1 = rotl_d(x1, 15); x1 ^= x0;
    x0 += x1; x1 = rotl_d(x1, 26); x1 ^= x0;
    x0 += x1; x1 = rotl_d(x1,  6); x1 ^= x0;
    x0 += k0; x1 += k1 + 3u;
    x0 += x1; x1 = rotl_d(x1, 17); x1 ^= x0;
    x0 += x1; x1 = rotl_d(x1, 29); x1 ^= x0;
    x0 += x1; x1 = rotl_d(x1, 16); x1 ^= x0;
    x0 += x1; x1 = rotl_d(x1, 24); x1 ^= x0;
    x0 += k1; x1 += k2 + 4u;
    x0 += x1; x1 = rotl_d(x1, 13); x1 ^= x0;
    x0 += x1; x1 = rotl_d(x1, 15); x1 ^= x0;
    x0 += x1; x1 = rotl_d(x1, 26); x1 ^= x0;
    x0 += x1; x1 = rotl_d(x1,  6); x1 ^= x0;
    x0 += k2; x1 += k0 + 5u;
}

// XLA ErfInv f32 (Giles polynomial); log1p(-x^2) -> fast v_log_f32 path
__device__ __forceinline__ float erfinv_f(float x) {
    float w = -__logf(fmaf(x, -x, 1.0f));
    float p;
    if (w < 5.0f) {
        w = w - 2.5f;
        p = 2.81022636e-08f;
        p = p * w + 3.43273939e-07f;
        p = p * w + -3.5233877e-06f;
        p = p * w + -4.39150654e-06f;
        p = p * w + 0.00021858087f;
        p = p * w + -0.00125372503f;
        p = p * w + -0.00417768164f;
        p = p * w + 0.246640727f;
        p = p * w + 1.50140941f;
    } else {
        w = sqrtf(w) - 3.0f;
        p = -0.000200214257f;
        p = p * w + 0.000100950558f;
        p = p * w + 0.00134934322f;
        p = p * w + -0.00367342844f;
        p = p * w + 0.00573950773f;
        p = p * w + -0.0076224613f;
        p = p * w + 0.00943887047f;
        p = p * w + 1.00167406f;
        p = p * w + 2.83297682f;
    }
    return p * x;
}

__device__ __forceinline__ float tf_normal(uint32_t k0, uint32_t k1, uint32_t idx) {
    uint32_t x0 = 0u, x1 = idx;
    tf2x32_d(k0, k1, x0, x1);
    uint32_t bits = x0 ^ x1;
    float f = __uint_as_float((bits >> 9) | 0x3f800000u) - 1.0f;
    float u = f * 2.0f - 0.99999994f;
    u = fmaxf(-0.99999994f, u);
    return 1.41421354f * erfinv_f(u);
}

// ---------- noise init: 4 elements/thread, bf16 out only ----------
__global__ __launch_bounds__(256) void noise_kernel(
    u16* __restrict__ xb,
    uint32_t ka0, uint32_t ka1, float ca,
    uint32_t kb0, uint32_t kb1, float cb, int n4)
{
    int i = blockIdx.x * 256 + threadIdx.x;
    if (i >= n4) return;
    ushort4 vb;
    #pragma unroll
    for (int e = 0; e < 4; ++e) {
        uint32_t idx = (uint32_t)(i * 4 + e);
        float a = ca * tf_normal(ka0, ka1, idx)
                + cb * tf_normal(kb0, kb1, idx);
        (&vb.x)[e] = f2bf(a);
    }
    ((ushort4*)xb)[i] = vb;
}

// ---------- merged weight convert ----------
__global__ __launch_bounds__(256) void cvt_all_kernel(
    const float* __restrict__ Wq, const float* __restrict__ Wk,
    const float* __restrict__ Wv, const float* __restrict__ Wo,
    const float* __restrict__ W1, const float* __restrict__ W2,
    const float* __restrict__ Wout, u16* __restrict__ dst, int n4)
{
    int i = blockIdx.x * 256 + threadIdx.x;
    if (i >= n4) return;
    int e = i * 4;
    const float* src;
    if (e < 3145728) {
        int l = e / 786432;
        int rem = e - l * 786432;
        int sel = rem >> 18;
        int off = rem & 262143;
        src = (sel == 0 ? Wq : sel == 1 ? Wk : Wv) + l * 262144 + off;
    } else if (e < 4194304) src = Wo + (e - 3145728);
    else if (e < 8388608)  src = W1 + (e - 4194304);
    else if (e < 12582912) src = W2 + (e - 8388608);
    else                   src = Wout + (e - 12582912);
    float4 v = *(const float4*)src;
    uint2 o;
    o.x = pk2bf(v.x, v.y);
    o.y = pk2bf(v.z, v.w);
    *(uint2*)(dst + e) = o;
}

// ---------- unified GEMM: 128x64 tile, 8 waves (512 thr), dbuf, XCD swizzle ---
// EPI: 0 = f32 out; 1 = bf16 out + bf16 resid; 2 = bf16 out + relu;
//      3 = QKV split
template<int EPI>
__global__ __launch_bounds__(512) void gemm64u(
    const u16* __restrict__ A, const u16* __restrict__ Bw,
    const float* __restrict__ bias0, const float* __restrict__ bias1,
    const float* __restrict__ bias2, const u16* __restrict__ resid,
    void* __restrict__ out0, void* __restrict__ out1, void* __restrict__ out2,
    int N, int K)
{
    constexpr int ACH = 16;
    constexpr int ASZ = 128 * 64, BSZ = 64 * 64;
    __shared__ __align__(16) u16 At[2 * ASZ];
    __shared__ __align__(16) u16 Bt[2 * BSZ];
    const int tid = threadIdx.x;
    const int l = tid & 63;
    const int w = tid >> 6;
    const int wr = w >> 1, wc = w & 1;

    int lid = blockIdx.y * gridDim.x + blockIdx.x;
    int nwg = gridDim.x * gridDim.y;
    int nlid = (lid & 7) * (nwg >> 3) + (lid >> 3);
    int mb = nlid / gridDim.x;
    int nb = nlid - mb * gridDim.x;

    const int lrow = l >> 3;
    const int lch  = (l & 7) ^ lrow;

    const u16* aTile = A  + (size_t)(mb * 128) * K + (size_t)lrow * K + lch * 8;
    const u16* bTile = Bw + (size_t)(nb * 64) * K + (size_t)lrow * K + lch * 8;

    f32x4 acc[2][2] = {};

    auto stage = [&](int buf, int k0) {
        #pragma unroll
        for (int i = 0; i < 3; ++i) {
            int c = w * 3 + i;
            if (c < ACH) gld16(aTile + (size_t)(c * 8) * K + k0, &At[buf * ASZ + c * 512]);
            else gld16(bTile + (size_t)((c - ACH) * 8) * K + k0, &Bt[buf * BSZ + (c - ACH) * 512]);
        }
    };
    auto compute = [&](int buf) {
        const u16* Ac = &At[buf * ASZ];
        const u16* Bc = &Bt[buf * BSZ];
        #pragma unroll
        for (int kc = 0; kc < 2; ++kc) {
            B8 af[2], bfr[2];
            #pragma unroll
            for (int m = 0; m < 2; ++m) {
                int r = wr * 32 + m * 16 + (l & 15);
                int ch = kc * 4 + (l >> 4);
                af[m].s = *(const s16x8*)&Ac[r * 64 + ((ch ^ (r & 7)) * 8)];
            }
            #pragma unroll
            for (int n = 0; n < 2; ++n) {
                int r = wc * 32 + n * 16 + (l & 15);
                int ch = kc * 4 + (l >> 4);
                bfr[n].s = *(const s16x8*)&Bc[r * 64 + ((ch ^ (r & 7)) * 8)];
            }
            #pragma unroll
            for (int m = 0; m < 2; ++m)
                #pragma unroll
                for (int n = 0; n < 2; ++n)
                    acc[m][n] = __builtin_amdgcn_mfma_f32_16x16x32_bf16(
                        af[m].b, bfr[n].b, acc[m][n], 0, 0, 0);
        }
    };

    stage(0, 0);
    __syncthreads();
    int cur = 0;
    for (int k0 = 0; k0 < K; k0 += 64) {
        if (k0 + 64 < K) stage(cur ^ 1, k0 + 64);
        compute(cur);
        __syncthreads();
        cur ^= 1;
    }

    if constexpr (EPI == 3) {
        int which = nb >> 3;
        int colseg = (nb & 7) * 64 + wc * 32;
        const float* biasp = which == 0 ? bias0 : which == 1 ? bias1 : bias2;
        float bcol[2];
        #pragma unroll
        for (int n = 0; n < 2; ++n)
            bcol[n] = biasp[colseg + n * 16 + (l & 15)];
        if (which == 2) {
            u16* vT = (u16*)out2;
            #pragma unroll
            for (int m = 0; m < 2; ++m) {
                int row0 = mb * 128 + wr * 32 + m * 16 + (l >> 4) * 4;
                int bb = row0 >> 10, s0 = row0 & 1023;
                #pragma unroll
                for (int n = 0; n < 2; ++n) {
                    int col = colseg + n * 16 + (l & 15);
                    int hh = col >> 6, dd = col & 63;
                    uint2 o;
                    o.x = pk2bf(acc[m][n][0] + bcol[n], acc[m][n][1] + bcol[n]);
                    o.y = pk2bf(acc[m][n][2] + bcol[n], acc[m][n][3] + bcol[n]);
                    *(uint2*)&vT[((size_t)((bb * 8 + hh) * 64 + dd)) * 1024 + s0] = o;
                }
            }
            return;
        }
        float oscale = (which == 0) ? 0.18033688f : 1.0f;  // 0.125*log2(e)
        u16* outp = (u16*)(which == 0 ? out0 : out1);
        #pragma unroll
        for (int m = 0; m < 2; ++m) {
            #pragma unroll
            for (int j = 0; j < 4; ++j) {
                int row = mb * 128 + wr * 32 + m * 16 + (l >> 4) * 4 + j;
                #pragma unroll
                for (int n = 0; n < 2; ++n) {
                    int col = colseg + n * 16 + (l & 15);
                    outp[(size_t)row * 512 + col] = f2bf((acc[m][n][j] + bcol[n]) * oscale);
                }
            }
        }
        return;
    }

    float bcol[2];
    #pragma unroll
    for (int n = 0; n < 2; ++n)
        bcol[n] = bias0[nb * 64 + wc * 32 + n * 16 + (l & 15)];

    #pragma unroll
    for (int m = 0; m < 2; ++m) {
        #pragma unroll
        for (int j = 0; j < 4; ++j) {
            int row = mb * 128 + wr * 32 + m * 16 + (l >> 4) * 4 + j;
            #pragma unroll
            for (int n = 0; n < 2; ++n) {
                int col = nb * 64 + wc * 32 + n * 16 + (l & 15);
                float v = acc[m][n][j] + bcol[n];
                if constexpr (EPI == 1) v += bf2f(resid[(size_t)row * N + col]);
                if constexpr (EPI == 2) v = fmaxf(v, 0.0f);
                if constexpr (EPI == 0) ((float*)out0)[(size_t)row * N + col] = v;
                else                    ((u16*)out0)[(size_t)row * N + col] = f2bf(v);
            }
        }
    }
}

// ---------- LayerNorm: bf16 in (y) -> bf16 out (xb). One wave per row of 512. -
__global__ __launch_bounds__(256) void ln_kernel(
    const u16* __restrict__ y, const float* __restrict__ g,
    const float* __restrict__ b, u16* __restrict__ xb)
{
    int row = blockIdx.x * 4 + (threadIdx.x >> 6);
    int l = threadIdx.x & 63;
    uint4 vv = ((const uint4*)(y + (size_t)row * 512))[l];
    uint32_t wsr[4] = {vv.x, vv.y, vv.z, vv.w};
    float xv[8];
    #pragma unroll
    for (int k = 0; k < 4; ++k) {
        xv[2 * k]     = __uint_as_float(wsr[k] << 16);
        xv[2 * k + 1] = __uint_as_float(wsr[k] & 0xFFFF0000u);
    }
    float s = 0.0f, q = 0.0f;
    #pragma unroll
    for (int k = 0; k < 8; ++k) { s += xv[k]; q += xv[k] * xv[k]; }
    #pragma unroll
    for (int m = 1; m < 64; m <<= 1) {
        s += __shfl_xor(s, m, 64);
        q += __shfl_xor(q, m, 64);
    }
    float mean = s * (1.0f / 512.0f);
    float var  = q * (1.0f / 512.0f) - mean * mean;
    float rstd = rsqrtf(var + 1e-5f);
    const float4* gv = (const float4*)g;
    const float4* bv = (const float4*)b;
    float4 g0 = gv[2 * l], g1 = gv[2 * l + 1];
    float4 b0 = bv[2 * l], b1 = bv[2 * l + 1];
    float ov[8];
    ov[0] = (xv[0] - mean) * rstd * g0.x + b0.x;
    ov[1] = (xv[1] - mean) * rstd * g0.y + b0.y;
    ov[2] = (xv[2] - mean) * rstd * g0.z + b0.z;
    ov[3] = (xv[3] - mean) * rstd * g0.w + b0.w;
    ov[4] = (xv[4] - mean) * rstd * g1.x + b1.x;
    ov[5] = (xv[5] - mean) * rstd * g1.y + b1.y;
    ov[6] = (xv[6] - mean) * rstd * g1.z + b1.z;
    ov[7] = (xv[7] - mean) * rstd * g1.w + b1.w;
    uint4 o;
    o.x = pk2bf(ov[0], ov[1]);
    o.y = pk2bf(ov[2], ov[3]);
    o.z = pk2bf(ov[4], ov[5]);
    o.w = pk2bf(ov[6], ov[7]);
    ((uint4*)(xb + (size_t)row * 512))[l] = o;
}

// ---------- fused attention v7: 8 waves x 16 q-rows, 2 blocks/CU, setprio -----
__global__ __launch_bounds__(512) void attn_kernel(
    const u16* __restrict__ Q, const u16* __restrict__ Km,
    const u16* __restrict__ vT, u16* __restrict__ O)
{
    __shared__ __align__(16) u16 Kt[2][64 * 64];
    __shared__ __align__(16) u16 Vt[2][64 * 64];
    __shared__ __align__(16) char Pl[8][2048];
    const int tid = threadIdx.x;
    const int l = tid & 63;
    const int w = tid >> 6;
    const int g = l >> 4;
    const int q15 = l & 15;
    const int bh = blockIdx.x;
    const int qb = blockIdx.y;
    const int b = bh >> 3, h = bh & 7;
    const int rowQ0 = b * 1024 + qb * 128 + w * 16;
    const int colh = h * 64;
    char* pl = &Pl[w][0];
    const int rbase = q15 * 128;
    const int sw = (q15 & 7) << 4;

    const int srow = l >> 3;
    const u16* Kbase = Km + (size_t)(b * 1024) * 512 + colh;
    const u16* Vbase = vT + (size_t)bh * 64 * 1024;

    B8 qf[2];
    #pragma unroll
    for (int kc = 0; kc < 2; ++kc)
        qf[kc].s = *(const s16x8*)&Q[(size_t)(rowQ0 + q15) * 512
                                     + colh + kc * 32 + g * 8];

    f32x4 oacc[4] = {};
    float lrun = 0.0f;

    auto stage = [&](int buf, int kt) {
        int r = w * 8 + srow;
        int cc = (l & 7) ^ (r & 7);
        gld16(Kbase + (size_t)(kt * 64 + r) * 512 + cc * 8, &Kt[buf][w * 512]);
        gld16(Vbase + (size_t)r * 1024 + kt * 64 + cc * 8, &Vt[buf][w * 512]);
    };

    stage(0, 0);
    __syncthreads();
    int cur = 0;

    for (int kt = 0; kt < 16; ++kt) {
        if (kt < 15) stage(cur ^ 1, kt + 1);
        const u16* KtL = &Kt[cur][0];
        const u16* VtL = &Vt[cur][0];

        f32x4 st[4];
        __builtin_amdgcn_s_setprio(1);
        #pragma unroll
        for (int mt = 0; mt < 4; ++mt) {
            int r = mt * 16 + q15;
            B8 kf0, kf1;
            kf0.s = *(const s16x8*)&KtL[r * 64 + ((g ^ (r & 7)) * 8)];
            kf1.s = *(const s16x8*)&KtL[r * 64 + (((4 + g) ^ (r & 7)) * 8)];
            f32x4 t = {0.f, 0.f, 0.f, 0.f};
            t = __builtin_amdgcn_mfma_f32_16x16x32_bf16(kf0.b, qf[0].b, t, 0, 0, 0);
            t = __builtin_amdgcn_mfma_f32_16x16x32_bf16(kf1.b, qf[1].b, t, 0, 0, 0);
            st[mt] = t;
        }
        __builtin_amdgcn_s_setprio(0);

        float rs = 0.0f;
        #pragma unroll
        for (int mt = 0; mt < 4; ++mt) {
            float e0 = fexp2(st[mt][0]);
            float e1 = fexp2(st[mt][1]);
            float e2 = fexp2(st[mt][2]);
            float e3 = fexp2(st[mt][3]);
            rs += (e0 + e1) + (e2 + e3);
            uint2 pk;
            pk.x = pk2bf(e0, e1);
            pk.y = pk2bf(e2, e3);
            *(uint2*)(pl + rbase + ((mt * 32 + g * 8) ^ sw)) = pk;
        }
        rs += __shfl_xor(rs, 16, 64);
        rs += __shfl_xor(rs, 32, 64);
        lrun += rs;

        B8 pf0, pf1;
        pf0.s = *(const s16x8*)(pl + rbase + ((g * 16) ^ sw));
        pf1.s = *(const s16x8*)(pl + rbase + (((4 + g) * 16) ^ sw));

        __builtin_amdgcn_s_setprio(1);
        #pragma unroll
        for (int dt = 0; dt < 4; ++dt) {
            int r = dt * 16 + q15;
            B8 vf0, vf1;
            vf0.s = *(const s16x8*)&VtL[r * 64 + ((g ^ (r & 7)) * 8)];
            vf1.s = *(const s16x8*)&VtL[r * 64 + (((4 + g) ^ (r & 7)) * 8)];
            oacc[dt] = __builtin_amdgcn_mfma_f32_16x16x32_bf16(
                vf0.b, pf0.b, oacc[dt], 0, 0, 0);
            oacc[dt] = __builtin_amdgcn_mfma_f32_16x16x32_bf16(
                vf1.b, pf1.b, oacc[dt], 0, 0, 0);
        }
        __builtin_amdgcn_s_setprio(0);
        __syncthreads();
        cur ^= 1;
    }

    float inv = 1.0f / lrun;
    int row = rowQ0 + q15;
    #pragma unroll
    for (int dt = 0; dt < 4; ++dt) {
        uint2 o;
        o.x = pk2bf(oacc[dt][0] * inv, oacc[dt][1] * inv);
        o.y = pk2bf(oacc[dt][2] * inv, oacc[dt][3] * inv);
        *(uint2*)&O[(size_t)row * 512 + colh + dt * 16 + g * 4] = o;
    }
}

// ---------- launcher ----------
extern "C" void kernel_launch(void* const* d_in, const int* in_sizes, int n_in,
                              void* d_out, int out_size, void* d_ws, size_t ws_size,
                              hipStream_t stream)
{
    const int D = 512, F = 2048, Lc = 4;
    const int Mrows = 8 * 1024;

    const float* Wq   = (const float*)d_in[1];
    const float* Wk   = (const float*)d_in[2];
    const float* Wv   = (const float*)d_in[3];
    const float* bq   = (const float*)d_in[4];
    const float* bk   = (const float*)d_in[5];
    const float* bv   = (const float*)d_in[6];
    const float* Wo   = (const float*)d_in[7];
    const float* bo   = (const float*)d_in[8];
    const float* ln1g = (const float*)d_in[9];
    const float* ln1b = (const float*)d_in[10];
    const float* ln2g = (const float*)d_in[11];
    const float* ln2b = (const float*)d_in[12];
    const float* W1   = (const float*)d_in[13];
    const float* b1   = (const float*)d_in[14];
    const float* W2   = (const float*)d_in[15];
    const float* b2   = (const float*)d_in[16];
    const float* Wout = (const float*)d_in[17];
    const float* bout = (const float*)d_in[18];

    char* p = (char*)d_ws;
    auto alloc = [&](size_t bytes) {
        char* r = p;
        p += (bytes + 255) & ~(size_t)255;
        return r;
    };
    u16* xb = (u16*)alloc((size_t)Mrows * D * 2);
    u16* y  = (u16*)alloc((size_t)Mrows * D * 2);
    char* pool = alloc((size_t)Mrows * F * 2);
    u16* qb_ = (u16*)pool;
    u16* kb_ = (u16*)(pool + (size_t)Mrows * D * 2);
    u16* vT  = (u16*)(pool + (size_t)Mrows * D * 2 * 2);
    u16* ao  = (u16*)(pool + (size_t)Mrows * D * 2 * 3);
    u16* ff1 = (u16*)pool;
    u16* wAll  = (u16*)alloc((size_t)12845056 * 2);
    u16* wqkvB = wAll;
    u16* woB   = wAll + 3145728;
    u16* w1B   = wAll + 4194304;
    u16* w2B   = wAll + 8388608;
    u16* woutB = wAll + 12582912;

    {
        int n4 = 12845056 / 4;
        cvt_all_kernel<<<(n4 + 255) / 256, 256, 0, stream>>>(
            Wq, Wk, Wv, Wo, W1, W2, Wout, wAll, n4);
    }

    // DDIM noise coefficients
    float ac[1000];
    {
        float start = 1e-4f, stop = 0.02f;
        float delta = (stop - start) / 999.0f;
        float prod = 1.0f;
        for (int i = 0; i < 1000; ++i) {
            float beta = start + (float)i * delta;
            prod *= (1.0f - beta);
            ac[i] = prod;
        }
    }
    int ts[2] = {999, 998};
    double cs[2];
    double tail = 1.0;
    for (int idx = 0; idx < 2; ++idx) {
        int t = ts[idx];
        cs[idx] = sqrt(1.0 - (double)ac[t]) * tail;
        tail *= sqrt((double)ac[t]);
    }
    uint32_t kk[2][2];
    for (int idx = 0; idx < 2; ++idx) {
        uint32_t x0 = 0u, x1 = (uint32_t)ts[idx];
        tf2x32_h(0u, 42u, x0, x1);
        kk[idx][0] = x0; kk[idx][1] = x1;
    }
    int n4tot = Mrows * D / 4;
    noise_kernel<<<(n4tot + 255) / 256, 256, 0, stream>>>(
        xb,
        kk[0][0], kk[0][1], (float)cs[0],
        kk[1][0], kk[1][1], (float)cs[1], n4tot);

    dim3 gqkv(3 * D / 64, Mrows / 128);    // (24, 64) = 1536
    dim3 g64(D / 64, Mrows / 128);         // (8, 64) = 512
    dim3 gff1(F / 64, Mrows / 128);        // (32, 64) = 2048

    for (int l = 0; l < Lc; ++l) {
        const u16* wqkv_l = wqkvB + (size_t)l * 3 * D * D;
        const u16* wo_l = woB + (size_t)l * D * D;
        const u16* w1_l = w1B + (size_t)l * F * D;
        const u16* w2_l = w2B + (size_t)l * D * F;

        gemm64u<3><<<gqkv, 512, 0, stream>>>(
            xb, wqkv_l, bq + l * D, bk + l * D, bv + l * D, nullptr,
            qb_, kb_, vT, 3 * D, D);
        attn_kernel<<<dim3(64, 8), 512, 0, stream>>>(qb_, kb_, vT, ao);
        gemm64u<1><<<g64, 512, 0, stream>>>(
            ao, wo_l, bo + l * D, nullptr, nullptr, xb,
            y, nullptr, nullptr, D, D);
        ln_kernel<<<Mrows / 4, 256, 0, stream>>>(y, ln1g + l * D, ln1b + l * D, xb);
        gemm64u<2><<<gff1, 512, 0, stream>>>(
            xb, w1_l, b1 + l * F, nullptr, nullptr, nullptr,
            ff1, nullptr, nullptr, F, D);
        gemm64u<1><<<g64, 512, 0, stream>>>(
            ff1, w2_l, b2 + l * D, nullptr, nullptr, xb,
            y, nullptr, nullptr, D, F);
        ln_kernel<<<Mrows / 4, 256, 0, stream>>>(y, ln2g + l * D, ln2b + l * D, xb);
    }
    gemm64u<0><<<g64, 512, 0, stream>>>(
        xb, woutB, bout, nullptr, nullptr, nullptr,
        d_out, nullptr, nullptr, D, D);
}

// Round 15
// 562.340 us; speedup vs baseline: 1.0414x; 1.0284x over previous
//
#include <hip/hip_runtime.h>
#include <stdint.h>
#include <math.h>

typedef unsigned short u16;
typedef __bf16 bf16x8 __attribute__((ext_vector_type(8)));
typedef float f32x4 __attribute__((ext_vector_type(4)));
typedef short s16x8 __attribute__((ext_vector_type(8)));
union B8 { s16x8 s; bf16x8 b; };

// ---------- helpers ----------
__device__ __forceinline__ u16 f2bf(float f) {
    union { __bf16 h; u16 u; } r;
    r.h = (__bf16)f;
    return r.u;
}
__device__ __forceinline__ uint32_t pk2bf(float a, float b) {
    union { __bf16 h[2]; uint32_t u; } r;
    r.h[0] = (__bf16)a; r.h[1] = (__bf16)b;
    return r.u;
}
__device__ __forceinline__ float bf2f(u16 u) {
    return __uint_as_float(((uint32_t)u) << 16);
}
__device__ __forceinline__ float fexp2(float x) {
    return __builtin_amdgcn_exp2f(x);   // raw v_exp_f32
}

typedef const __attribute__((address_space(1))) uint32_t* gas_t;
typedef __attribute__((address_space(3))) uint32_t* las_t;
__device__ __forceinline__ void gld16(const void* g, void* l) {
    __builtin_amdgcn_global_load_lds((gas_t)g, (las_t)l, 16, 0, 0);
}

__host__ __forceinline__ uint32_t rotl32(uint32_t x, int d) {
    return (x << d) | (x >> (32 - d));
}
__device__ __forceinline__ uint32_t rotl_d(uint32_t x, int d) {
    return __builtin_amdgcn_alignbit(x, x, (uint32_t)(32 - d));
}

// JAX threefry2x32 (20 rounds) — host version (key folding)
__host__ inline void tf2x32_h(uint32_t k0, uint32_t k1, uint32_t& x0, uint32_t& x1) {
    uint32_t k2 = k0 ^ k1 ^ 0x1BD11BDAu;
    x0 += k0; x1 += k1;
    x0 += x1; x1 = rotl32(x1, 13); x1 ^= x0;
    x0 += x1; x1 = rotl32(x1, 15); x1 ^= x0;
    x0 += x1; x1 = rotl32(x1, 26); x1 ^= x0;
    x0 += x1; x1 = rotl32(x1,  6); x1 ^= x0;
    x0 += k1; x1 += k2 + 1u;
    x0 += x1; x1 = rotl32(x1, 17); x1 ^= x0;
    x0 += x1; x1 = rotl32(x1, 29); x1 ^= x0;
    x0 += x1; x1 = rotl32(x1, 16); x1 ^= x0;
    x0 += x1; x1 = rotl32(x1, 24); x1 ^= x0;
    x0 += k2; x1 += k0 + 2u;
    x0 += x1; x1 = rotl32(x1, 13); x1 ^= x0;
    x0 += x1; x1 = rotl32(x1, 15); x1 ^= x0;
    x0 += x1; x1 = rotl32(x1, 26); x1 ^= x0;
    x0 += x1; x1 = rotl32(x1,  6); x1 ^= x0;
    x0 += k0; x1 += k1 + 3u;
    x0 += x1; x1 = rotl32(x1, 17); x1 ^= x0;
    x0 += x1; x1 = rotl32(x1, 29); x1 ^= x0;
    x0 += x1; x1 = rotl32(x1, 16); x1 ^= x0;
    x0 += x1; x1 = rotl32(x1, 24); x1 ^= x0;
    x0 += k1; x1 += k2 + 4u;
    x0 += x1; x1 = rotl32(x1, 13); x1 ^= x0;
    x0 += x1; x1 = rotl32(x1, 15); x1 ^= x0;
    x0 += x1; x1 = rotl32(x1, 26); x1 ^= x0;
    x0 += x1; x1 = rotl32(x1,  6); x1 ^= x0;
    x0 += k2; x1 += k0 + 5u;
}

__device__ __forceinline__ void tf2x32_d(uint32_t k0, uint32_t k1,
                                         uint32_t& x0, uint32_t& x1) {
    uint32_t k2 = k0 ^ k1 ^ 0x1BD11BDAu;
    x0 += k0; x1 += k1;
    x0 += x1; x1 = rotl_d(x1, 13); x1 ^= x0;
    x0 += x1; x1 = rotl_d(x1, 15); x1 ^= x0;
    x0 += x1; x1 = rotl_d(x1, 26); x1 ^= x0;
    x0 += x1; x1 = rotl_d(x1,  6); x1 ^= x0;
    x0 += k1; x1 += k2 + 1u;
    x0 += x1; x1 = rotl_d(x1, 17); x1 ^= x0;
    x0 += x1; x1 = rotl_d(x1, 29); x1 ^= x0;
    x0 += x1; x1 = rotl_d(x1, 16); x1 ^= x0;
    x0 += x1; x1 = rotl_d(x1, 24); x1 ^= x0;
    x0 += k2; x1 += k0 + 2u;
    x0 += x1; x1 = rotl_d(x1, 13); x1 ^= x0;
    x0 += x1; x1 = rotl_d(x1, 15); x1 ^= x0;
    x0 += x1; x1 = rotl_d(x1, 26); x1 ^= x0;
    x0 += x1; x1 = rotl_d(x1,  6); x1 ^= x0;
    x0 += k0; x1 += k1 + 3u;
    x0 += x1; x1 = rotl_d(x1, 17); x1 ^= x0;
    x0 += x1; x1 = rotl_d(x1, 29); x1 ^= x0;
    x0 += x1; x1 = rotl_d(x1, 16); x1 ^= x0;
    x0 += x1; x1 = rotl_d(x1, 24); x1 ^= x0;
    x0 += k1; x1 += k2 + 4u;
    x0 += x1; x1 = rotl_d(x1, 13); x1 ^= x0;
    x0 += x1; x1 = rotl_d(x1, 15); x1 ^= x0;
    x0 += x1; x1 = rotl_d(x1, 26); x1 ^= x0;
    x0 += x1; x1 = rotl_d(x1,  6); x1 ^= x0;
    x0 += k2; x1 += k0 + 5u;
}

// XLA ErfInv f32 (Giles polynomial); log1p(-x^2) -> fast v_log_f32 path
__device__ __forceinline__ float erfinv_f(float x) {
    float w = -__logf(fmaf(x, -x, 1.0f));
    float p;
    if (w < 5.0f) {
        w = w - 2.5f;
        p = 2.81022636e-08f;
        p = p * w + 3.43273939e-07f;
        p = p * w + -3.5233877e-06f;
        p = p * w + -4.39150654e-06f;
        p = p * w + 0.00021858087f;
        p = p * w + -0.00125372503f;
        p = p * w + -0.00417768164f;
        p = p * w + 0.246640727f;
        p = p * w + 1.50140941f;
    } else {
        w = sqrtf(w) - 3.0f;
        p = -0.000200214257f;
        p = p * w + 0.000100950558f;
        p = p * w + 0.00134934322f;
        p = p * w + -0.00367342844f;
        p = p * w + 0.00573950773f;
        p = p * w + -0.0076224613f;
        p = p * w + 0.00943887047f;
        p = p * w + 1.00167406f;
        p = p * w + 2.83297682f;
    }
    return p * x;
}

__device__ __forceinline__ float tf_normal(uint32_t k0, uint32_t k1, uint32_t idx) {
    uint32_t x0 = 0u, x1 = idx;
    tf2x32_d(k0, k1, x0, x1);
    uint32_t bits = x0 ^ x1;
    float f = __uint_as_float((bits >> 9) | 0x3f800000u) - 1.0f;
    float u = f * 2.0f - 0.99999994f;
    u = fmaxf(-0.99999994f, u);
    return 1.41421354f * erfinv_f(u);
}

// ---------- noise init: 4 elements/thread, bf16 out only ----------
__global__ __launch_bounds__(256) void noise_kernel(
    u16* __restrict__ xb,
    uint32_t ka0, uint32_t ka1, float ca,
    uint32_t kb0, uint32_t kb1, float cb, int n4)
{
    int i = blockIdx.x * 256 + threadIdx.x;
    if (i >= n4) return;
    ushort4 vb;
    #pragma unroll
    for (int e = 0; e < 4; ++e) {
        uint32_t idx = (uint32_t)(i * 4 + e);
        float a = ca * tf_normal(ka0, ka1, idx)
                + cb * tf_normal(kb0, kb1, idx);
        (&vb.x)[e] = f2bf(a);
    }
    ((ushort4*)xb)[i] = vb;
}

// ---------- merged weight convert ----------
__global__ __launch_bounds__(256) void cvt_all_kernel(
    const float* __restrict__ Wq, const float* __restrict__ Wk,
    const float* __restrict__ Wv, const float* __restrict__ Wo,
    const float* __restrict__ W1, const float* __restrict__ W2,
    const float* __restrict__ Wout, u16* __restrict__ dst, int n4)
{
    int i = blockIdx.x * 256 + threadIdx.x;
    if (i >= n4) return;
    int e = i * 4;
    const float* src;
    if (e < 3145728) {
        int l = e / 786432;
        int rem = e - l * 786432;
        int sel = rem >> 18;
        int off = rem & 262143;
        src = (sel == 0 ? Wq : sel == 1 ? Wk : Wv) + l * 262144 + off;
    } else if (e < 4194304) src = Wo + (e - 3145728);
    else if (e < 8388608)  src = W1 + (e - 4194304);
    else if (e < 12582912) src = W2 + (e - 8388608);
    else                   src = Wout + (e - 12582912);
    float4 v = *(const float4*)src;
    uint2 o;
    o.x = pk2bf(v.x, v.y);
    o.y = pk2bf(v.z, v.w);
    *(uint2*)(dst + e) = o;
}

// ---------- unified GEMM: 128x64 tile, 8 waves (512 thr), XCD swizzle --------
// T4 counted-vmcnt pipeline: raw s_barrier (no drain) + vmcnt(3) keeps the
// next tile's 3 loads in flight across the barrier.
// EPI: 0 = f32 out; 1 = bf16 out + bf16 resid; 2 = bf16 out + relu;
//      3 = QKV split
template<int EPI>
__global__ __launch_bounds__(512) void gemm64u(
    const u16* __restrict__ A, const u16* __restrict__ Bw,
    const float* __restrict__ bias0, const float* __restrict__ bias1,
    const float* __restrict__ bias2, const u16* __restrict__ resid,
    void* __restrict__ out0, void* __restrict__ out1, void* __restrict__ out2,
    int N, int K)
{
    constexpr int ACH = 16;
    constexpr int ASZ = 128 * 64, BSZ = 64 * 64;
    __shared__ __align__(16) u16 At[2 * ASZ];
    __shared__ __align__(16) u16 Bt[2 * BSZ];
    const int tid = threadIdx.x;
    const int l = tid & 63;
    const int w = tid >> 6;
    const int wr = w >> 1, wc = w & 1;

    int lid = blockIdx.y * gridDim.x + blockIdx.x;
    int nwg = gridDim.x * gridDim.y;
    int nlid = (lid & 7) * (nwg >> 3) + (lid >> 3);
    int mb = nlid / gridDim.x;
    int nb = nlid - mb * gridDim.x;

    const int lrow = l >> 3;
    const int lch  = (l & 7) ^ lrow;

    const u16* aTile = A  + (size_t)(mb * 128) * K + (size_t)lrow * K + lch * 8;
    const u16* bTile = Bw + (size_t)(nb * 64) * K + (size_t)lrow * K + lch * 8;

    f32x4 acc[2][2] = {};

    auto stage = [&](int buf, int k0) {
        #pragma unroll
        for (int i = 0; i < 3; ++i) {
            int c = w * 3 + i;
            if (c < ACH) gld16(aTile + (size_t)(c * 8) * K + k0, &At[buf * ASZ + c * 512]);
            else gld16(bTile + (size_t)((c - ACH) * 8) * K + k0, &Bt[buf * BSZ + (c - ACH) * 512]);
        }
    };
    auto compute = [&](int buf) {
        const u16* Ac = &At[buf * ASZ];
        const u16* Bc = &Bt[buf * BSZ];
        #pragma unroll
        for (int kc = 0; kc < 2; ++kc) {
            B8 af[2], bfr[2];
            #pragma unroll
            for (int m = 0; m < 2; ++m) {
                int r = wr * 32 + m * 16 + (l & 15);
                int ch = kc * 4 + (l >> 4);
                af[m].s = *(const s16x8*)&Ac[r * 64 + ((ch ^ (r & 7)) * 8)];
            }
            #pragma unroll
            for (int n = 0; n < 2; ++n) {
                int r = wc * 32 + n * 16 + (l & 15);
                int ch = kc * 4 + (l >> 4);
                bfr[n].s = *(const s16x8*)&Bc[r * 64 + ((ch ^ (r & 7)) * 8)];
            }
            #pragma unroll
            for (int m = 0; m < 2; ++m)
                #pragma unroll
                for (int n = 0; n < 2; ++n)
                    acc[m][n] = __builtin_amdgcn_mfma_f32_16x16x32_bf16(
                        af[m].b, bfr[n].b, acc[m][n], 0, 0, 0);
        }
    };

    // T4 pipeline: 2 buffers, counted vmcnt, raw barriers (no vmcnt(0) drain).
    stage(0, 0);
    stage(1, 64);
    int k0 = 0;
    for (; k0 < K - 64; k0 += 64) {
        int buf = (k0 >> 6) & 1;
        asm volatile("s_waitcnt vmcnt(3)" ::: "memory");   // oldest stage landed
        __builtin_amdgcn_s_barrier();                      // all waves' writes visible
        compute(buf);
        __builtin_amdgcn_s_barrier();                      // all waves done reading buf
        if (k0 + 128 < K) stage(buf, k0 + 128);            // safe to overwrite
    }
    asm volatile("s_waitcnt vmcnt(0)" ::: "memory");       // final tile fully landed
    __builtin_amdgcn_s_barrier();
    compute((k0 >> 6) & 1);

    if constexpr (EPI == 3) {
        int which = nb >> 3;
        int colseg = (nb & 7) * 64 + wc * 32;
        const float* biasp = which == 0 ? bias0 : which == 1 ? bias1 : bias2;
        float bcol[2];
        #pragma unroll
        for (int n = 0; n < 2; ++n)
            bcol[n] = biasp[colseg + n * 16 + (l & 15)];
        if (which == 2) {
            u16* vT = (u16*)out2;
            #pragma unroll
            for (int m = 0; m < 2; ++m) {
                int row0 = mb * 128 + wr * 32 + m * 16 + (l >> 4) * 4;
                int bb = row0 >> 10, s0 = row0 & 1023;
                #pragma unroll
                for (int n = 0; n < 2; ++n) {
                    int col = colseg + n * 16 + (l & 15);
                    int hh = col >> 6, dd = col & 63;
                    uint2 o;
                    o.x = pk2bf(acc[m][n][0] + bcol[n], acc[m][n][1] + bcol[n]);
                    o.y = pk2bf(acc[m][n][2] + bcol[n], acc[m][n][3] + bcol[n]);
                    *(uint2*)&vT[((size_t)((bb * 8 + hh) * 64 + dd)) * 1024 + s0] = o;
                }
            }
            return;
        }
        float oscale = (which == 0) ? 0.18033688f : 1.0f;  // 0.125*log2(e)
        u16* outp = (u16*)(which == 0 ? out0 : out1);
        #pragma unroll
        for (int m = 0; m < 2; ++m) {
            #pragma unroll
            for (int j = 0; j < 4; ++j) {
                int row = mb * 128 + wr * 32 + m * 16 + (l >> 4) * 4 + j;
                #pragma unroll
                for (int n = 0; n < 2; ++n) {
                    int col = colseg + n * 16 + (l & 15);
                    outp[(size_t)row * 512 + col] = f2bf((acc[m][n][j] + bcol[n]) * oscale);
                }
            }
        }
        return;
    }

    float bcol[2];
    #pragma unroll
    for (int n = 0; n < 2; ++n)
        bcol[n] = bias0[nb * 64 + wc * 32 + n * 16 + (l & 15)];

    #pragma unroll
    for (int m = 0; m < 2; ++m) {
        #pragma unroll
        for (int j = 0; j < 4; ++j) {
            int row = mb * 128 + wr * 32 + m * 16 + (l >> 4) * 4 + j;
            #pragma unroll
            for (int n = 0; n < 2; ++n) {
                int col = nb * 64 + wc * 32 + n * 16 + (l & 15);
                float v = acc[m][n][j] + bcol[n];
                if constexpr (EPI == 1) v += bf2f(resid[(size_t)row * N + col]);
                if constexpr (EPI == 2) v = fmaxf(v, 0.0f);
                if constexpr (EPI == 0) ((float*)out0)[(size_t)row * N + col] = v;
                else                    ((u16*)out0)[(size_t)row * N + col] = f2bf(v);
            }
        }
    }
}

// ---------- LayerNorm: bf16 in (y) -> bf16 out (xb). One wave per row of 512. -
__global__ __launch_bounds__(256) void ln_kernel(
    const u16* __restrict__ y, const float* __restrict__ g,
    const float* __restrict__ b, u16* __restrict__ xb)
{
    int row = blockIdx.x * 4 + (threadIdx.x >> 6);
    int l = threadIdx.x & 63;
    uint4 vv = ((const uint4*)(y + (size_t)row * 512))[l];
    uint32_t wsr[4] = {vv.x, vv.y, vv.z, vv.w};
    float xv[8];
    #pragma unroll
    for (int k = 0; k < 4; ++k) {
        xv[2 * k]     = __uint_as_float(wsr[k] << 16);
        xv[2 * k + 1] = __uint_as_float(wsr[k] & 0xFFFF0000u);
    }
    float s = 0.0f, q = 0.0f;
    #pragma unroll
    for (int k = 0; k < 8; ++k) { s += xv[k]; q += xv[k] * xv[k]; }
    #pragma unroll
    for (int m = 1; m < 64; m <<= 1) {
        s += __shfl_xor(s, m, 64);
        q += __shfl_xor(q, m, 64);
    }
    float mean = s * (1.0f / 512.0f);
    float var  = q * (1.0f / 512.0f) - mean * mean;
    float rstd = rsqrtf(var + 1e-5f);
    const float4* gv = (const float4*)g;
    const float4* bv = (const float4*)b;
    float4 g0 = gv[2 * l], g1 = gv[2 * l + 1];
    float4 b0 = bv[2 * l], b1 = bv[2 * l + 1];
    float ov[8];
    ov[0] = (xv[0] - mean) * rstd * g0.x + b0.x;
    ov[1] = (xv[1] - mean) * rstd * g0.y + b0.y;
    ov[2] = (xv[2] - mean) * rstd * g0.z + b0.z;
    ov[3] = (xv[3] - mean) * rstd * g0.w + b0.w;
    ov[4] = (xv[4] - mean) * rstd * g1.x + b1.x;
    ov[5] = (xv[5] - mean) * rstd * g1.y + b1.y;
    ov[6] = (xv[6] - mean) * rstd * g1.z + b1.z;
    ov[7] = (xv[7] - mean) * rstd * g1.w + b1.w;
    uint4 o;
    o.x = pk2bf(ov[0], ov[1]);
    o.y = pk2bf(ov[2], ov[3]);
    o.z = pk2bf(ov[4], ov[5]);
    o.w = pk2bf(ov[6], ov[7]);
    ((uint4*)(xb + (size_t)row * 512))[l] = o;
}

// ---------- fused attention v7: 8 waves x 16 q-rows, 2 blocks/CU, setprio -----
__global__ __launch_bounds__(512) void attn_kernel(
    const u16* __restrict__ Q, const u16* __restrict__ Km,
    const u16* __restrict__ vT, u16* __restrict__ O)
{
    __shared__ __align__(16) u16 Kt[2][64 * 64];
    __shared__ __align__(16) u16 Vt[2][64 * 64];
    __shared__ __align__(16) char Pl[8][2048];
    const int tid = threadIdx.x;
    const int l = tid & 63;
    const int w = tid >> 6;
    const int g = l >> 4;
    const int q15 = l & 15;
    const int bh = blockIdx.x;
    const int qb = blockIdx.y;
    const int b = bh >> 3, h = bh & 7;
    const int rowQ0 = b * 1024 + qb * 128 + w * 16;
    const int colh = h * 64;
    char* pl = &Pl[w][0];
    const int rbase = q15 * 128;
    const int sw = (q15 & 7) << 4;

    const int srow = l >> 3;
    const u16* Kbase = Km + (size_t)(b * 1024) * 512 + colh;
    const u16* Vbase = vT + (size_t)bh * 64 * 1024;

    B8 qf[2];
    #pragma unroll
    for (int kc = 0; kc < 2; ++kc)
        qf[kc].s = *(const s16x8*)&Q[(size_t)(rowQ0 + q15) * 512
                                     + colh + kc * 32 + g * 8];

    f32x4 oacc[4] = {};
    float lrun = 0.0f;

    auto stage = [&](int buf, int kt) {
        int r = w * 8 + srow;
        int cc = (l & 7) ^ (r & 7);
        gld16(Kbase + (size_t)(kt * 64 + r) * 512 + cc * 8, &Kt[buf][w * 512]);
        gld16(Vbase + (size_t)r * 1024 + kt * 64 + cc * 8, &Vt[buf][w * 512]);
    };

    stage(0, 0);
    __syncthreads();
    int cur = 0;

    for (int kt = 0; kt < 16; ++kt) {
        if (kt < 15) stage(cur ^ 1, kt + 1);
        const u16* KtL = &Kt[cur][0];
        const u16* VtL = &Vt[cur][0];

        f32x4 st[4];
        __builtin_amdgcn_s_setprio(1);
        #pragma unroll
        for (int mt = 0; mt < 4; ++mt) {
            int r = mt * 16 + q15;
            B8 kf0, kf1;
            kf0.s = *(const s16x8*)&KtL[r * 64 + ((g ^ (r & 7)) * 8)];
            kf1.s = *(const s16x8*)&KtL[r * 64 + (((4 + g) ^ (r & 7)) * 8)];
            f32x4 t = {0.f, 0.f, 0.f, 0.f};
            t = __builtin_amdgcn_mfma_f32_16x16x32_bf16(kf0.b, qf[0].b, t, 0, 0, 0);
            t = __builtin_amdgcn_mfma_f32_16x16x32_bf16(kf1.b, qf[1].b, t, 0, 0, 0);
            st[mt] = t;
        }
        __builtin_amdgcn_s_setprio(0);

        float rs = 0.0f;
        #pragma unroll
        for (int mt = 0; mt < 4; ++mt) {
            float e0 = fexp2(st[mt][0]);
            float e1 = fexp2(st[mt][1]);
            float e2 = fexp2(st[mt][2]);
            float e3 = fexp2(st[mt][3]);
            rs += (e0 + e1) + (e2 + e3);
            uint2 pk;
            pk.x = pk2bf(e0, e1);
            pk.y = pk2bf(e2, e3);
            *(uint2*)(pl + rbase + ((mt * 32 + g * 8) ^ sw)) = pk;
        }
        rs += __shfl_xor(rs, 16, 64);
        rs += __shfl_xor(rs, 32, 64);
        lrun += rs;

        B8 pf0, pf1;
        pf0.s = *(const s16x8*)(pl + rbase + ((g * 16) ^ sw));
        pf1.s = *(const s16x8*)(pl + rbase + (((4 + g) * 16) ^ sw));

        __builtin_amdgcn_s_setprio(1);
        #pragma unroll
        for (int dt = 0; dt < 4; ++dt) {
            int r = dt * 16 + q15;
            B8 vf0, vf1;
            vf0.s = *(const s16x8*)&VtL[r * 64 + ((g ^ (r & 7)) * 8)];
            vf1.s = *(const s16x8*)&VtL[r * 64 + (((4 + g) ^ (r & 7)) * 8)];
            oacc[dt] = __builtin_amdgcn_mfma_f32_16x16x32_bf16(
                vf0.b, pf0.b, oacc[dt], 0, 0, 0);
            oacc[dt] = __builtin_amdgcn_mfma_f32_16x16x32_bf16(
                vf1.b, pf1.b, oacc[dt], 0, 0, 0);
        }
        __builtin_amdgcn_s_setprio(0);
        __syncthreads();
        cur ^= 1;
    }

    float inv = 1.0f / lrun;
    int row = rowQ0 + q15;
    #pragma unroll
    for (int dt = 0; dt < 4; ++dt) {
        uint2 o;
        o.x = pk2bf(oacc[dt][0] * inv, oacc[dt][1] * inv);
        o.y = pk2bf(oacc[dt][2] * inv, oacc[dt][3] * inv);
        *(uint2*)&O[(size_t)row * 512 + colh + dt * 16 + g * 4] = o;
    }
}

// ---------- launcher ----------
extern "C" void kernel_launch(void* const* d_in, const int* in_sizes, int n_in,
                              void* d_out, int out_size, void* d_ws, size_t ws_size,
                              hipStream_t stream)
{
    const int D = 512, F = 2048, Lc = 4;
    const int Mrows = 8 * 1024;

    const float* Wq   = (const float*)d_in[1];
    const float* Wk   = (const float*)d_in[2];
    const float* Wv   = (const float*)d_in[3];
    const float* bq   = (const float*)d_in[4];
    const float* bk   = (const float*)d_in[5];
    const float* bv   = (const float*)d_in[6];
    const float* Wo   = (const float*)d_in[7];
    const float* bo   = (const float*)d_in[8];
    const float* ln1g = (const float*)d_in[9];
    const float* ln1b = (const float*)d_in[10];
    const float* ln2g = (const float*)d_in[11];
    const float* ln2b = (const float*)d_in[12];
    const float* W1   = (const float*)d_in[13];
    const float* b1   = (const float*)d_in[14];
    const float* W2   = (const float*)d_in[15];
    const float* b2   = (const float*)d_in[16];
    const float* Wout = (const float*)d_in[17];
    const float* bout = (const float*)d_in[18];

    char* p = (char*)d_ws;
    auto alloc = [&](size_t bytes) {
        char* r = p;
        p += (bytes + 255) & ~(size_t)255;
        return r;
    };
    u16* xb = (u16*)alloc((size_t)Mrows * D * 2);
    u16* y  = (u16*)alloc((size_t)Mrows * D * 2);
    char* pool = alloc((size_t)Mrows * F * 2);
    u16* qb_ = (u16*)pool;
    u16* kb_ = (u16*)(pool + (size_t)Mrows * D * 2);
    u16* vT  = (u16*)(pool + (size_t)Mrows * D * 2 * 2);
    u16* ao  = (u16*)(pool + (size_t)Mrows * D * 2 * 3);
    u16* ff1 = (u16*)pool;
    u16* wAll  = (u16*)alloc((size_t)12845056 * 2);
    u16* wqkvB = wAll;
    u16* woB   = wAll + 3145728;
    u16* w1B   = wAll + 4194304;
    u16* w2B   = wAll + 8388608;
    u16* woutB = wAll + 12582912;

    {
        int n4 = 12845056 / 4;
        cvt_all_kernel<<<(n4 + 255) / 256, 256, 0, stream>>>(
            Wq, Wk, Wv, Wo, W1, W2, Wout, wAll, n4);
    }

    // DDIM noise coefficients
    float ac[1000];
    {
        float start = 1e-4f, stop = 0.02f;
        float delta = (stop - start) / 999.0f;
        float prod = 1.0f;
        for (int i = 0; i < 1000; ++i) {
            float beta = start + (float)i * delta;
            prod *= (1.0f - beta);
            ac[i] = prod;
        }
    }
    int ts[2] = {999, 998};
    double cs[2];
    double tail = 1.0;
    for (int idx = 0; idx < 2; ++idx) {
        int t = ts[idx];
        cs[idx] = sqrt(1.0 - (double)ac[t]) * tail;
        tail *= sqrt((double)ac[t]);
    }
    uint32_t kk[2][2];
    for (int idx = 0; idx < 2; ++idx) {
        uint32_t x0 = 0u, x1 = (uint32_t)ts[idx];
        tf2x32_h(0u, 42u, x0, x1);
        kk[idx][0] = x0; kk[idx][1] = x1;
    }
    int n4tot = Mrows * D / 4;
    noise_kernel<<<(n4tot + 255) / 256, 256, 0, stream>>>(
        xb,
        kk[0][0], kk[0][1], (float)cs[0],
        kk[1][0], kk[1][1], (float)cs[1], n4tot);

    dim3 gqkv(3 * D / 64, Mrows / 128);    // (24, 64) = 1536
    dim3 g64(D / 64, Mrows / 128);         // (8, 64) = 512
    dim3 gff1(F / 64, Mrows / 128);        // (32, 64) = 2048

    for (int l = 0; l < Lc; ++l) {
        const u16* wqkv_l = wqkvB + (size_t)l * 3 * D * D;
        const u16* wo_l = woB + (size_t)l * D * D;
        const u16* w1_l = w1B + (size_t)l * F * D;
        const u16* w2_l = w2B + (size_t)l * D * F;

        gemm64u<3><<<gqkv, 512, 0, stream>>>(
            xb, wqkv_l, bq + l * D, bk + l * D, bv + l * D, nullptr,
            qb_, kb_, vT, 3 * D, D);
        attn_kernel<<<dim3(64, 8), 512, 0, stream>>>(qb_, kb_, vT, ao);
        gemm64u<1><<<g64, 512, 0, stream>>>(
            ao, wo_l, bo + l * D, nullptr, nullptr, xb,
            y, nullptr, nullptr, D, D);
        ln_kernel<<<Mrows / 4, 256, 0, stream>>>(y, ln1g + l * D, ln1b + l * D, xb);
        gemm64u<2><<<gff1, 512, 0, stream>>>(
            xb, w1_l, b1 + l * F, nullptr, nullptr, nullptr,
            ff1, nullptr, nullptr, F, D);
        gemm64u<1><<<g64, 512, 0, stream>>>(
            ff1, w2_l, b2 + l * D, nullptr, nullptr, xb,
            y, nullptr, nullptr, D, F);
        ln_kernel<<<Mrows / 4, 256, 0, stream>>>(y, ln2g + l * D, ln2b + l * D, xb);
    }
    gemm64u<0><<<g64, 512, 0, stream>>>(
        xb, woutB, bout, nullptr, nullptr, nullptr,
        d_out, nullptr, nullptr, D, D);
}